// Round 3
// baseline (175.724 us; speedup 1.0000x reference)
//
#include <hip/hip_runtime.h>
#include <hip/hip_cooperative_groups.h>
#include <math.h>

namespace cg = cooperative_groups;

#define A_N 2048
#define L_N 512
#define D 128
#define B_N 64
#define H1_N 512
#define H2_N 256
#define NCHUNK 8
#define CL 64     // L-chunk per score unit
#define TA 32     // atom tile
#define LDST 132  // padded LDS stride (floats)

// smem layout (floats)
#define OFF_XS   8448            // after Ps[64][132]
#define OFF_CRED 12672           // after Xs[32][132]
#define OFF_EWS  13712           // after cred[16][65]
#define OFF_PSUM 13776           // ews[64]
#define SMEM_F   14032           // + psum[2][128]

__device__ __forceinline__ int lb_dev(const int* __restrict__ arr, int n, int val) {
    int lo = 0, hi = n;
    while (lo < hi) { int mid = (lo + hi) >> 1; if (arr[mid] < val) lo = mid + 1; else hi = mid; }
    return lo;
}

__device__ __forceinline__ float blk_sum(float v, float* red, int tid) {
    #pragma unroll
    for (int off = 32; off >= 1; off >>= 1) v += __shfl_xor(v, off);
    __syncthreads();
    if ((tid & 63) == 0) red[tid >> 6] = v;
    __syncthreads();
    return red[0] + red[1] + red[2] + red[3];
}

__global__ __launch_bounds__(256) void fused_all(
        const float* __restrict__ atom_embed, const float* __restrict__ prot,
        const int* __restrict__ splits, const float* __restrict__ W_att,
        const float* __restrict__ W1, const float* __restrict__ b1,
        const float* __restrict__ W2, const float* __restrict__ b2,
        const float* __restrict__ Wo, const float* __restrict__ bo,
        float* __restrict__ X, float* __restrict__ rowmaxp,
        float* __restrict__ ppart, float* __restrict__ eWpart,
        float* __restrict__ HcT, float* __restrict__ H1T,
        float* __restrict__ out) {
    cg::grid_group grid = cg::this_grid();
    __shared__ float smem[SMEM_F];
    __shared__ float red[4];
    const int tid = threadIdx.x;
    const int bid = blockIdx.x;

    // ================= P1: X = atom_embed @ W_att =================
    {
        float (*ae)[128] = (float(*)[128])smem;
        const int a0 = bid * 8;
        float4 v = reinterpret_cast<const float4*>(atom_embed + (size_t)a0 * D)[tid];
        const int fi = tid * 4;
        *reinterpret_cast<float4*>(&ae[fi >> 7][fi & 127]) = v;
        __syncthreads();
        const int d = tid & 127;
        const int ai = tid >> 7;
        float acc0 = 0.f, acc1 = 0.f, acc2 = 0.f, acc3 = 0.f;
        for (int k = 0; k < D; ++k) {
            const float w = W_att[k * D + d];
            acc0 += ae[ai + 0][k] * w;
            acc1 += ae[ai + 2][k] * w;
            acc2 += ae[ai + 4][k] * w;
            acc3 += ae[ai + 6][k] * w;
        }
        X[(size_t)(a0 + ai + 0) * D + d] = acc0;
        X[(size_t)(a0 + ai + 2) * D + d] = acc1;
        X[(size_t)(a0 + ai + 4) * D + d] = acc2;
        X[(size_t)(a0 + ai + 6) * D + d] = acc3;
    }
    grid.sync();

    // ====== P2: scores -> rowmax partials + prot-pool partials ======
    {
        float (*Ps)[LDST]  = (float(*)[LDST])smem;
        float (*Xs)[LDST]  = (float(*)[LDST])(smem + OFF_XS);
        float (*cred)[65]  = (float(*)[65])(smem + OFF_CRED);
        float* ews         = smem + OFF_EWS;
        float (*psum)[128] = (float(*)[128])(smem + OFF_PSUM);
        const int b = bid & (B_N - 1);
        const int s = lb_dev(splits, A_N, b);
        const int e = lb_dev(splits, A_N, b + 1);
        const int n = e - s;
        const int ti = tid >> 4;   // 0..15 -> atoms ti*2, ti*2+1
        const int tj = tid & 15;   // l = li*16 + tj

        for (int half = 0; half < 2; ++half) {
            const int chunk = (bid >> 6) + 4 * half;   // 0..7
            const int l0 = chunk * CL;
            __syncthreads();  // previous smem use complete

            // stage prot chunk [64][128]
            {
                const float4* src = reinterpret_cast<const float4*>(prot + ((size_t)b * L_N + l0) * D);
                for (int i = tid; i < CL * (D / 4); i += 256) {
                    float4 v = src[i];
                    *reinterpret_cast<float4*>(&Ps[i >> 5][(i & 31) * 4]) = v;
                }
            }

            float cmax[4] = {-INFINITY, -INFINITY, -INFINITY, -INFINITY};
            const int natile = (n + TA - 1) / TA;
            for (int at = 0; at < natile; ++at) {
                __syncthreads();
                {
                    const float4* xsrc = reinterpret_cast<const float4*>(X + (size_t)s * D);
                    for (int i = tid; i < TA * (D / 4); i += 256) {
                        const int j = i >> 5;
                        const int aidx = at * TA + j;
                        float4 v;
                        if (aidx < n) v = xsrc[(size_t)aidx * (D / 4) + (i & 31)];
                        else { v.x = 0.f; v.y = 0.f; v.z = 0.f; v.w = 0.f; }
                        *reinterpret_cast<float4*>(&Xs[j][(i & 31) * 4]) = v;
                    }
                }
                __syncthreads();

                float acc[2][4];
                #pragma unroll
                for (int r = 0; r < 2; ++r)
                    #pragma unroll
                    for (int c = 0; c < 4; ++c) acc[r][c] = 0.f;

                #pragma unroll 2
                for (int k = 0; k < D; k += 4) {
                    const float4 x0 = *reinterpret_cast<const float4*>(&Xs[ti * 2 + 0][k]);
                    const float4 x1 = *reinterpret_cast<const float4*>(&Xs[ti * 2 + 1][k]);
                    #pragma unroll
                    for (int li = 0; li < 4; ++li) {
                        const float4 p = *reinterpret_cast<const float4*>(&Ps[li * 16 + tj][k]);
                        acc[0][li] += x0.x * p.x + x0.y * p.y + x0.z * p.z + x0.w * p.w;
                        acc[1][li] += x1.x * p.x + x1.y * p.y + x1.z * p.z + x1.w * p.w;
                    }
                }

                const int a0i = at * TA + ti * 2;
                const bool v0 = a0i < n, v1 = (a0i + 1) < n;
                float rm0 = -INFINITY, rm1 = -INFINITY;
                #pragma unroll
                for (int li = 0; li < 4; ++li) {
                    rm0 = fmaxf(rm0, acc[0][li]);
                    rm1 = fmaxf(rm1, acc[1][li]);
                    if (v0) cmax[li] = fmaxf(cmax[li], acc[0][li]);
                    if (v1) cmax[li] = fmaxf(cmax[li], acc[1][li]);
                }
                #pragma unroll
                for (int off = 8; off >= 1; off >>= 1) {
                    rm0 = fmaxf(rm0, __shfl_xor(rm0, off, 16));
                    rm1 = fmaxf(rm1, __shfl_xor(rm1, off, 16));
                }
                if (tj == 0) {
                    if (v0) rowmaxp[(size_t)(s + a0i) * NCHUNK + chunk] = rm0;
                    if (v1) rowmaxp[(size_t)(s + a0i + 1) * NCHUNK + chunk] = rm1;
                }
            }

            // column max over atoms -> ews[l] = exp(colmax)
            #pragma unroll
            for (int li = 0; li < 4; ++li) cred[ti][li * 16 + tj] = cmax[li];
            __syncthreads();
            if (tid < CL) {
                float m = -INFINITY;
                #pragma unroll
                for (int t = 0; t < 16; ++t) m = fmaxf(m, cred[t][tid]);
                ews[tid] = __expf(m) == __expf(m) ? expf(m) : expf(m);  // plain expf
            }
            __syncthreads();

            // prot-pool partial: pp[d] = sum_l ews[l] * Ps[l][d]
            {
                const int d = tid & 127;
                const int hh = tid >> 7;
                float pp = 0.f;
                #pragma unroll 4
                for (int i = 0; i < 32; ++i)
                    pp += ews[hh * 32 + i] * Ps[hh * 32 + i][d];
                psum[hh][d] = pp;
            }
            __syncthreads();
            if (tid < 128)
                ppart[(size_t)(b * NCHUNK + chunk) * D + tid] = psum[0][tid] + psum[1][tid];
            if (tid < 64) {
                float v = ews[tid];
                #pragma unroll
                for (int off = 32; off >= 1; off >>= 1) v += __shfl_xor(v, off);
                if (tid == 0) eWpart[b * NCHUNK + chunk] = v;
            }
        }
    }
    grid.sync();

    // ================= P3: pools -> HcT [256][64] =================
    {
        const int b = bid >> 2;
        const int dq = bid & 3;   // d-quarter (32 dims)
        const int s = lb_dev(splits, A_N, b);
        const int e = lb_dev(splits, A_N, b + 1);
        const int n = e - s;
        float* coef = smem;                         // [512]
        float4* pred = (float4*)(smem + 512);       // [32][8]

        float local = 0.f;
        for (int j = tid; j < n; j += 256) {
            const float* rp = rowmaxp + (size_t)(s + j) * NCHUNK;
            float m = rp[0];
            #pragma unroll
            for (int c = 1; c < NCHUNK; ++c) m = fmaxf(m, rp[c]);
            local += expf(m);
        }
        const float Sc = blk_sum(local, red, tid);

        float eWsum = 0.f;
        #pragma unroll
        for (int c = 0; c < NCHUNK; ++c) eWsum += eWpart[b * NCHUNK + c];

        const int dI = tid & 7;    // float4 within 32-dim slice
        const int ag = tid >> 3;   // 0..31 atom group
        const float4* ae4 = reinterpret_cast<const float4*>(atom_embed);
        float4 pool = {0.f, 0.f, 0.f, 0.f};
        for (int t0 = 0; t0 < n; t0 += 512) {
            const int cnt = min(512, n - t0);
            __syncthreads();
            for (int j = tid; j < cnt; j += 256) {
                const float* rp = rowmaxp + (size_t)(s + t0 + j) * NCHUNK;
                float m = rp[0];
                #pragma unroll
                for (int c = 1; c < NCHUNK; ++c) m = fmaxf(m, rp[c]);
                coef[j] = expf(m) / Sc;
            }
            __syncthreads();
            for (int j = ag; j < cnt; j += 32) {
                const float c = coef[j];
                const float4 v = ae4[(size_t)(s + t0 + j) * (D / 4) + dq * 8 + dI];
                pool.x += c * v.x; pool.y += c * v.y; pool.z += c * v.z; pool.w += c * v.w;
            }
        }
        __syncthreads();
        pred[ag * 8 + dI] = pool;
        __syncthreads();
        #pragma unroll
        for (int off = 16; off >= 1; off >>= 1) {
            if (ag < off) {
                float4 o = pred[(ag + off) * 8 + dI];
                float4 m = pred[ag * 8 + dI];
                m.x += o.x; m.y += o.y; m.z += o.z; m.w += o.w;
                pred[ag * 8 + dI] = m;
            }
            __syncthreads();
        }
        if (tid < 8) {
            const float4 acc = pred[tid];
            const int dbase = dq * 32 + tid * 4;
            HcT[(size_t)(dbase + 0) * B_N + b] = acc.x;
            HcT[(size_t)(dbase + 1) * B_N + b] = acc.y;
            HcT[(size_t)(dbase + 2) * B_N + b] = acc.z;
            HcT[(size_t)(dbase + 3) * B_N + b] = acc.w;
        }
        if (tid < 32) {
            const int d = dq * 32 + tid;
            float v = 0.f;
            #pragma unroll
            for (int c = 0; c < NCHUNK; ++c) v += ppart[(size_t)(b * NCHUNK + c) * D + d];
            HcT[(size_t)(D + d) * B_N + b] = v / eWsum;
        }
    }
    grid.sync();

    // ================= P4: H1T = relu(Hc@W1+b1)^T =================
    {
        const int m = tid & 63;
        const int jh = (tid >> 6) & 1;
        const int kh = tid >> 7;
        const int j = bid * 2 + jh;
        float acc = 0.f;
        const int k0 = kh * 128;
        #pragma unroll 8
        for (int k = k0; k < k0 + 128; ++k)
            acc += HcT[(size_t)k * B_N + m] * W1[(size_t)k * H1_N + j];
        float (*hr)[64] = (float(*)[64])smem;
        __syncthreads();
        hr[jh * 2 + kh][m] = acc;
        __syncthreads();
        if (kh == 0)
            H1T[(size_t)j * B_N + m] = fmaxf(hr[jh * 2][m] + hr[jh * 2 + 1][m] + b1[j], 0.f);
        if (bid == 0 && tid < B_N) out[tid] = bo[0];
    }
    grid.sync();

    // ================= P5: H2 + output =================
    {
        const int m = tid & 63;
        const int kq = tid >> 6;
        const int j = bid;
        float acc = 0.f;
        const int k0 = kq * 128;
        #pragma unroll 8
        for (int k = k0; k < k0 + 128; ++k)
            acc += H1T[(size_t)k * B_N + m] * W2[(size_t)k * H2_N + j];
        float (*hr)[64] = (float(*)[64])smem;
        __syncthreads();
        hr[kq][m] = acc;
        __syncthreads();
        if (kq == 0) {
            const float h2 = fmaxf(hr[0][m] + hr[1][m] + hr[2][m] + hr[3][m] + b2[j], 0.f);
            atomicAdd(out + m, h2 * Wo[j]);
        }
    }
}

extern "C" void kernel_launch(void* const* d_in, const int* in_sizes, int n_in,
                              void* d_out, int out_size, void* d_ws, size_t ws_size,
                              hipStream_t stream) {
    const float* atom_embed = (const float*)d_in[0];
    const float* prot       = (const float*)d_in[1];
    const int*   splits     = (const int*)d_in[2];
    const float* W_att      = (const float*)d_in[3];
    const float* W1         = (const float*)d_in[4];
    const float* b1         = (const float*)d_in[5];
    const float* W2         = (const float*)d_in[6];
    const float* b2         = (const float*)d_in[7];
    const float* Wo         = (const float*)d_in[8];
    const float* bo         = (const float*)d_in[9];
    float* out = (float*)d_out;

    float* ws = (float*)d_ws;
    float* X       = ws;  ws += A_N * D;             // 262144
    float* rowmaxp = ws;  ws += A_N * NCHUNK;        // 16384
    float* ppart   = ws;  ws += B_N * NCHUNK * D;    // 65536
    float* eWpart  = ws;  ws += B_N * NCHUNK;        // 512
    float* HcT     = ws;  ws += 2 * D * B_N;         // 16384
    float* H1T     = ws;  ws += H1_N * B_N;          // 32768

    void* args[] = {
        (void*)&atom_embed, (void*)&prot, (void*)&splits, (void*)&W_att,
        (void*)&W1, (void*)&b1, (void*)&W2, (void*)&b2, (void*)&Wo, (void*)&bo,
        (void*)&X, (void*)&rowmaxp, (void*)&ppart, (void*)&eWpart,
        (void*)&HcT, (void*)&H1T, (void*)&out
    };
    hipLaunchCooperativeKernel((void*)fused_all, dim3(256), dim3(256), args, 0, stream);
}

// Round 4
// 63.635 us; speedup vs baseline: 2.7614x; 2.7614x over previous
//
#include <hip/hip_runtime.h>
#include <math.h>

#define A_N 2048
#define L_N 512
#define D 128
#define B_N 64
#define H1_N 512
#define H2_N 256
#define NCHUNK 8
#define CL 64     // L-chunk per score block
#define TA 32     // atom tile
#define LDST 132  // padded LDS stride (floats)

// smem float offsets for k2
#define OFF_XS   8448            // after Ps[64][132]
#define OFF_CRED 12672           // after Xs[32][132]
#define OFF_EWS  13712           // after cred[16][65]
#define OFF_PSUM 13776           // after ews[64]
#define SMEM_F   14032           // + psum[2][128]

__device__ __forceinline__ int lb_dev(const int* __restrict__ arr, int n, int val) {
    int lo = 0, hi = n;
    while (lo < hi) { int mid = (lo + hi) >> 1; if (arr[mid] < val) lo = mid + 1; else hi = mid; }
    return lo;
}

__device__ __forceinline__ float blk_sum(float v, float* red, int tid) {
    #pragma unroll
    for (int off = 32; off >= 1; off >>= 1) v += __shfl_xor(v, off);
    __syncthreads();
    if ((tid & 63) == 0) red[tid >> 6] = v;
    __syncthreads();
    return red[0] + red[1] + red[2] + red[3];
}

// ---------- K1: X = atom_embed @ W_att ; zero cnt ; out = bo ----------
__global__ __launch_bounds__(256) void k1_xmul(const float* __restrict__ atom_embed,
                                               const float* __restrict__ W_att,
                                               const float* __restrict__ bo,
                                               float* __restrict__ X,
                                               float* __restrict__ out,
                                               int* __restrict__ cnt) {
    __shared__ float ae[8][128];
    const int tid = threadIdx.x;
    const int bid = blockIdx.x;
    if (bid == 0 && tid < B_N) { cnt[tid] = 0; out[tid] = bo[0]; }
    const int a0 = bid * 8;
    float4 v = reinterpret_cast<const float4*>(atom_embed + (size_t)a0 * D)[tid];
    const int fi = tid * 4;
    *reinterpret_cast<float4*>(&ae[fi >> 7][fi & 127]) = v;
    __syncthreads();
    const int d = tid & 127;
    const int ai = tid >> 7;
    float acc0 = 0.f, acc1 = 0.f, acc2 = 0.f, acc3 = 0.f;
    for (int k = 0; k < D; ++k) {
        const float w = W_att[k * D + d];
        acc0 += ae[ai + 0][k] * w;
        acc1 += ae[ai + 2][k] * w;
        acc2 += ae[ai + 4][k] * w;
        acc3 += ae[ai + 6][k] * w;
    }
    X[(size_t)(a0 + ai + 0) * D + d] = acc0;
    X[(size_t)(a0 + ai + 2) * D + d] = acc1;
    X[(size_t)(a0 + ai + 4) * D + d] = acc2;
    X[(size_t)(a0 + ai + 6) * D + d] = acc3;
}

// ---------- K2: scores + prot-pool partials; last block per molecule pools -> HcT ----------
__global__ __launch_bounds__(256) void k2_scores(const float* __restrict__ X,
                                                 const float* __restrict__ prot,
                                                 const float* __restrict__ atom_embed,
                                                 const int* __restrict__ splits,
                                                 float* __restrict__ rowmaxp,
                                                 float* __restrict__ ppart,
                                                 float* __restrict__ eWpart,
                                                 float* __restrict__ HcT,
                                                 int* __restrict__ cnt) {
    __shared__ float smem[SMEM_F];
    __shared__ float red[4];
    __shared__ int isLast;
    float (*Ps)[LDST]  = (float(*)[LDST])smem;
    float (*Xs)[LDST]  = (float(*)[LDST])(smem + OFF_XS);
    float (*cred)[65]  = (float(*)[65])(smem + OFF_CRED);
    float* ews         = smem + OFF_EWS;
    float (*psum)[128] = (float(*)[128])(smem + OFF_PSUM);

    const int tid = threadIdx.x;
    const int bid = blockIdx.x;
    const int b = bid & (B_N - 1);
    const int chunk = bid >> 6;            // 0..7
    const int l0 = chunk * CL;
    const int s = lb_dev(splits, A_N, b);
    const int e = lb_dev(splits, A_N, b + 1);
    const int n = e - s;
    const int ti = tid >> 4;   // 0..15 -> atoms ti*2, ti*2+1
    const int tj = tid & 15;   // l = li*16 + tj

    // stage prot chunk [64][128]
    {
        const float4* src = reinterpret_cast<const float4*>(prot + ((size_t)b * L_N + l0) * D);
        for (int i = tid; i < CL * (D / 4); i += 256) {
            float4 v = src[i];
            *reinterpret_cast<float4*>(&Ps[i >> 5][(i & 31) * 4]) = v;
        }
    }

    float cmax[4] = {-INFINITY, -INFINITY, -INFINITY, -INFINITY};
    const int natile = (n + TA - 1) / TA;
    for (int at = 0; at < natile; ++at) {
        __syncthreads();
        {
            const float4* xsrc = reinterpret_cast<const float4*>(X + (size_t)s * D);
            for (int i = tid; i < TA * (D / 4); i += 256) {
                const int j = i >> 5;
                const int aidx = at * TA + j;
                float4 v;
                if (aidx < n) v = xsrc[(size_t)aidx * (D / 4) + (i & 31)];
                else { v.x = 0.f; v.y = 0.f; v.z = 0.f; v.w = 0.f; }
                *reinterpret_cast<float4*>(&Xs[j][(i & 31) * 4]) = v;
            }
        }
        __syncthreads();

        float acc[2][4];
        #pragma unroll
        for (int r = 0; r < 2; ++r)
            #pragma unroll
            for (int c = 0; c < 4; ++c) acc[r][c] = 0.f;

        #pragma unroll 2
        for (int k = 0; k < D; k += 4) {
            const float4 x0 = *reinterpret_cast<const float4*>(&Xs[ti * 2 + 0][k]);
            const float4 x1 = *reinterpret_cast<const float4*>(&Xs[ti * 2 + 1][k]);
            #pragma unroll
            for (int li = 0; li < 4; ++li) {
                const float4 p = *reinterpret_cast<const float4*>(&Ps[li * 16 + tj][k]);
                acc[0][li] += x0.x * p.x + x0.y * p.y + x0.z * p.z + x0.w * p.w;
                acc[1][li] += x1.x * p.x + x1.y * p.y + x1.z * p.z + x1.w * p.w;
            }
        }

        const int a0i = at * TA + ti * 2;
        const bool v0 = a0i < n, v1 = (a0i + 1) < n;
        float rm0 = -INFINITY, rm1 = -INFINITY;
        #pragma unroll
        for (int li = 0; li < 4; ++li) {
            rm0 = fmaxf(rm0, acc[0][li]);
            rm1 = fmaxf(rm1, acc[1][li]);
            if (v0) cmax[li] = fmaxf(cmax[li], acc[0][li]);
            if (v1) cmax[li] = fmaxf(cmax[li], acc[1][li]);
        }
        #pragma unroll
        for (int off = 8; off >= 1; off >>= 1) {
            rm0 = fmaxf(rm0, __shfl_xor(rm0, off, 16));
            rm1 = fmaxf(rm1, __shfl_xor(rm1, off, 16));
        }
        if (tj == 0) {
            if (v0) rowmaxp[(size_t)(s + a0i) * NCHUNK + chunk] = rm0;
            if (v1) rowmaxp[(size_t)(s + a0i + 1) * NCHUNK + chunk] = rm1;
        }
    }

    // column max over atoms -> ews[l] = exp(colmax)
    #pragma unroll
    for (int li = 0; li < 4; ++li) cred[ti][li * 16 + tj] = cmax[li];
    __syncthreads();
    if (tid < CL) {
        float m = -INFINITY;
        #pragma unroll
        for (int t = 0; t < 16; ++t) m = fmaxf(m, cred[t][tid]);
        ews[tid] = expf(m);
    }
    __syncthreads();

    // prot-pool partial: pp[d] = sum_l ews[l] * Ps[l][d]
    {
        const int d = tid & 127;
        const int hh = tid >> 7;
        float pp = 0.f;
        #pragma unroll 4
        for (int i = 0; i < 32; ++i)
            pp += ews[hh * 32 + i] * Ps[hh * 32 + i][d];
        psum[hh][d] = pp;
    }
    __syncthreads();
    if (tid < 128)
        ppart[(size_t)(b * NCHUNK + chunk) * D + tid] = psum[0][tid] + psum[1][tid];
    if (tid < 64) {
        float v = ews[tid];
        #pragma unroll
        for (int off = 32; off >= 1; off >>= 1) v += __shfl_xor(v, off);
        if (tid == 0) eWpart[b * NCHUNK + chunk] = v;
    }
    __syncthreads();

    // ---- last-arrival: 8th block of this molecule does the pooling ----
    if (tid == 0) {
        __threadfence();  // release this block's global writes (device scope)
        int old = __hip_atomic_fetch_add(&cnt[b], 1, __ATOMIC_ACQ_REL, __HIP_MEMORY_SCOPE_AGENT);
        isLast = (old == NCHUNK - 1) ? 1 : 0;
    }
    __syncthreads();
    if (!isLast) return;
    if (tid == 0) __threadfence();  // acquire: see siblings' rowmaxp/ppart/eWpart
    __syncthreads();

    float* coef  = smem;                       // [512]
    float4* pred = (float4*)(smem + 512);      // [8][32]

    // Sc = sum_a exp(max over chunks)
    float local = 0.f;
    for (int j = tid; j < n; j += 256) {
        const float* rp = rowmaxp + (size_t)(s + j) * NCHUNK;
        float m = rp[0];
        #pragma unroll
        for (int c = 1; c < NCHUNK; ++c) m = fmaxf(m, rp[c]);
        local += expf(m);
    }
    const float Sc = blk_sum(local, red, tid);

    // atom pool
    const int dI = tid & 31;   // float4 column (128 dims)
    const int ag = tid >> 5;   // 0..7 atom group
    const float4* ae4 = reinterpret_cast<const float4*>(atom_embed);
    float4 pool = {0.f, 0.f, 0.f, 0.f};
    for (int t0 = 0; t0 < n; t0 += 512) {
        const int cnt2 = min(512, n - t0);
        __syncthreads();
        for (int j = tid; j < cnt2; j += 256) {
            const float* rp = rowmaxp + (size_t)(s + t0 + j) * NCHUNK;
            float m = rp[0];
            #pragma unroll
            for (int c = 1; c < NCHUNK; ++c) m = fmaxf(m, rp[c]);
            coef[j] = expf(m) / Sc;
        }
        __syncthreads();
        for (int j = ag; j < cnt2; j += 8) {
            const float c = coef[j];
            const float4 v = ae4[(size_t)(s + t0 + j) * (D / 4) + dI];
            pool.x += c * v.x; pool.y += c * v.y; pool.z += c * v.z; pool.w += c * v.w;
        }
    }
    __syncthreads();
    pred[ag * 32 + dI] = pool;
    __syncthreads();
    if (ag == 0) {
        float4 acc = pred[dI];
        #pragma unroll
        for (int gg = 1; gg < 8; ++gg) {
            const float4 t = pred[gg * 32 + dI];
            acc.x += t.x; acc.y += t.y; acc.z += t.z; acc.w += t.w;
        }
        HcT[(size_t)(dI * 4 + 0) * B_N + b] = acc.x;
        HcT[(size_t)(dI * 4 + 1) * B_N + b] = acc.y;
        HcT[(size_t)(dI * 4 + 2) * B_N + b] = acc.z;
        HcT[(size_t)(dI * 4 + 3) * B_N + b] = acc.w;
    }
    // prot pool combine
    if (tid < 128) {
        float v = 0.f, ez = 0.f;
        #pragma unroll
        for (int c = 0; c < NCHUNK; ++c) {
            v  += ppart[(size_t)(b * NCHUNK + c) * D + tid];
            ez += eWpart[b * NCHUNK + c];
        }
        HcT[(size_t)(D + tid) * B_N + b] = v / ez;
    }
}

// ---------- K4: H1T = relu(Hc @ W1 + b1)^T ----------
__global__ __launch_bounds__(256) void k4_h1(const float* __restrict__ HcT,
                                             const float* __restrict__ W1,
                                             const float* __restrict__ b1,
                                             float* __restrict__ H1T) {
    __shared__ float hr[4][64];
    const int tid = threadIdx.x;
    const int m = tid & 63;
    const int jh = (tid >> 6) & 1;
    const int kh = tid >> 7;
    const int j = blockIdx.x * 2 + jh;
    float acc = 0.f;
    const int k0 = kh * 128;
    #pragma unroll 8
    for (int k = k0; k < k0 + 128; ++k)
        acc += HcT[(size_t)k * B_N + m] * W1[(size_t)k * H1_N + j];
    hr[jh * 2 + kh][m] = acc;
    __syncthreads();
    if (kh == 0)
        H1T[(size_t)j * B_N + m] = fmaxf(hr[jh * 2][m] + hr[jh * 2 + 1][m] + b1[j], 0.f);
}

// ---------- K5: H2 + output atomics ----------
__global__ __launch_bounds__(256) void k5_h2(const float* __restrict__ H1T,
                                             const float* __restrict__ W2,
                                             const float* __restrict__ b2,
                                             const float* __restrict__ Wo,
                                             float* __restrict__ out) {
    __shared__ float hr[4][64];
    const int tid = threadIdx.x;
    const int m = tid & 63;
    const int kq = tid >> 6;
    const int j = blockIdx.x;
    float acc = 0.f;
    const int k0 = kq * 128;
    #pragma unroll 8
    for (int k = k0; k < k0 + 128; ++k)
        acc += H1T[(size_t)k * B_N + m] * W2[(size_t)k * H2_N + j];
    hr[kq][m] = acc;
    __syncthreads();
    if (kq == 0) {
        const float h2 = fmaxf(hr[0][m] + hr[1][m] + hr[2][m] + hr[3][m] + b2[j], 0.f);
        atomicAdd(out + m, h2 * Wo[j]);
    }
}

extern "C" void kernel_launch(void* const* d_in, const int* in_sizes, int n_in,
                              void* d_out, int out_size, void* d_ws, size_t ws_size,
                              hipStream_t stream) {
    const float* atom_embed = (const float*)d_in[0];
    const float* prot       = (const float*)d_in[1];
    const int*   splits     = (const int*)d_in[2];
    const float* W_att      = (const float*)d_in[3];
    const float* W1         = (const float*)d_in[4];
    const float* b1         = (const float*)d_in[5];
    const float* W2         = (const float*)d_in[6];
    const float* b2         = (const float*)d_in[7];
    const float* Wo         = (const float*)d_in[8];
    const float* bo         = (const float*)d_in[9];
    float* out = (float*)d_out;

    float* ws = (float*)d_ws;
    float* X       = ws;  ws += A_N * D;             // 262144
    float* rowmaxp = ws;  ws += A_N * NCHUNK;        // 16384
    float* ppart   = ws;  ws += B_N * NCHUNK * D;    // 65536
    float* eWpart  = ws;  ws += B_N * NCHUNK;        // 512
    float* HcT     = ws;  ws += 2 * D * B_N;         // 16384
    float* H1T     = ws;  ws += H1_N * B_N;          // 32768
    int*   cnt     = (int*)ws;                       // 64

    hipLaunchKernelGGL(k1_xmul,  dim3(A_N / 8),      dim3(256), 0, stream,
                       atom_embed, W_att, bo, X, out, cnt);
    hipLaunchKernelGGL(k2_scores,dim3(B_N * NCHUNK), dim3(256), 0, stream,
                       X, prot, atom_embed, splits, rowmaxp, ppart, eWpart, HcT, cnt);
    hipLaunchKernelGGL(k4_h1,    dim3(H1_N / 2),     dim3(256), 0, stream, HcT, W1, b1, H1T);
    hipLaunchKernelGGL(k5_h2,    dim3(H2_N),         dim3(256), 0, stream, H1T, W2, b2, Wo, out);
}

// Round 5
// 46.233 us; speedup vs baseline: 3.8008x; 1.3764x over previous
//
#include <hip/hip_runtime.h>
#include <math.h>

#define A_N 2048
#define L_N 512
#define D 128
#define B_N 64
#define H1_N 512
#define H2_N 256
#define NCHUNK 8
#define CL 64     // L-chunk per score block
#define XT 32     // atoms per X tile
#define PST 136   // bf16 LDS row stride (272 B = 17*16: aligned, 2-way bank alias on frags)

typedef __attribute__((ext_vector_type(8))) short short8;
typedef __attribute__((ext_vector_type(4))) float f32x4;

__device__ __forceinline__ int lb_dev(const int* __restrict__ arr, int n, int val) {
    int lo = 0, hi = n;
    while (lo < hi) { int mid = (lo + hi) >> 1; if (arr[mid] < val) lo = mid + 1; else hi = mid; }
    return lo;
}

__device__ __forceinline__ float blk_sum(float v, float* red, int tid) {
    #pragma unroll
    for (int off = 32; off >= 1; off >>= 1) v += __shfl_xor(v, off);
    __syncthreads();
    if ((tid & 63) == 0) red[tid >> 6] = v;
    __syncthreads();
    return red[0] + red[1] + red[2] + red[3];
}

// round-to-nearest-even f32 -> bf16 bits
__device__ __forceinline__ unsigned short f2bf(float f) {
    unsigned int u = __float_as_uint(f);
    return (unsigned short)((u + 0x7FFFu + ((u >> 16) & 1u)) >> 16);
}
__device__ __forceinline__ float bf2f(unsigned short h) {
    return __uint_as_float(((unsigned int)h) << 16);
}

// ---------- K1: X = atom_embed @ W_att ; out = bo ----------
__global__ __launch_bounds__(256) void k1_xmul(const float* __restrict__ atom_embed,
                                               const float* __restrict__ W_att,
                                               const float* __restrict__ bo,
                                               float* __restrict__ X,
                                               float* __restrict__ out) {
    __shared__ float ae[8][128];
    const int tid = threadIdx.x;
    const int bid = blockIdx.x;
    if (bid == 0 && tid < B_N) out[tid] = bo[0];
    const int a0 = bid * 8;
    float4 v = reinterpret_cast<const float4*>(atom_embed + (size_t)a0 * D)[tid];
    const int fi = tid * 4;
    *reinterpret_cast<float4*>(&ae[fi >> 7][fi & 127]) = v;
    __syncthreads();
    const int d = tid & 127;
    const int ai = tid >> 7;
    float acc0 = 0.f, acc1 = 0.f, acc2 = 0.f, acc3 = 0.f;
    for (int k = 0; k < D; ++k) {
        const float w = W_att[k * D + d];
        acc0 += ae[ai + 0][k] * w;
        acc1 += ae[ai + 2][k] * w;
        acc2 += ae[ai + 4][k] * w;
        acc3 += ae[ai + 6][k] * w;
    }
    X[(size_t)(a0 + ai + 0) * D + d] = acc0;
    X[(size_t)(a0 + ai + 2) * D + d] = acc1;
    X[(size_t)(a0 + ai + 4) * D + d] = acc2;
    X[(size_t)(a0 + ai + 6) * D + d] = acc3;
}

// ---------- K2: MFMA split-bf16 scores -> rowmax partials + prot-pool partials ----------
// LDS layout (bytes): Ph[64][136]bf16 @0, Pl @17408, Xh[32][136] @34816, Xl @43520,
// rm_lds[4][32]f32 @52224. ews[64]/psum[256] overlay on Xh after the score loop.
__global__ __launch_bounds__(256) void k2_scores(const float* __restrict__ X,
                                                 const float* __restrict__ prot,
                                                 const int* __restrict__ splits,
                                                 float* __restrict__ rowmaxp,
                                                 float* __restrict__ ppart,
                                                 float* __restrict__ eWpart) {
    __shared__ __align__(16) unsigned char lds[52736];
    unsigned short* Ph = (unsigned short*)lds;            // [CL][PST]
    unsigned short* Pl = Ph + CL * PST;
    unsigned short* Xh = Pl + CL * PST;                   // [XT][PST]
    unsigned short* Xl = Xh + XT * PST;
    float* rm_lds = (float*)(lds + 52224);                // [4][32]

    const int tid = threadIdx.x;
    const int bid = blockIdx.x;
    const int b = bid & (B_N - 1);
    const int chunk = bid >> 6;           // 0..7 (same XCD for all chunks of b)
    const int l0 = chunk * CL;
    const int s = lb_dev(splits, A_N, b);
    const int e = lb_dev(splits, A_N, b + 1);
    const int n = e - s;
    const int lane = tid & 63;
    const int w = tid >> 6;               // wave 0..3 -> l-tile w*16..w*16+15
    const int col = lane & 15;
    const int kb = lane >> 4;             // k-subblock 0..3

    // stage P chunk [64][128] f32 -> bf16 hi/lo
    {
        const float4* src = (const float4*)(prot + ((size_t)b * L_N + l0) * D);
        for (int i = tid; i < CL * (D / 4); i += 256) {
            float4 v = src[i];
            const int row = i >> 5, q = (i & 31) * 4;
            ushort4 h, lo;
            h.x = f2bf(v.x); lo.x = f2bf(v.x - bf2f(h.x));
            h.y = f2bf(v.y); lo.y = f2bf(v.y - bf2f(h.y));
            h.z = f2bf(v.z); lo.z = f2bf(v.z - bf2f(h.z));
            h.w = f2bf(v.w); lo.w = f2bf(v.w - bf2f(h.w));
            *(ushort4*)(Ph + row * PST + q) = h;
            *(ushort4*)(Pl + row * PST + q) = lo;
        }
    }
    __syncthreads();

    // B fragments for this wave's 16 l's: lane reads P[w*16+col][ks*32 + kb*8 .. +8]
    short8 Bh[4], Bl[4];
    {
        const int rowb = w * 16 + col;
        #pragma unroll
        for (int ks = 0; ks < 4; ++ks) {
            Bh[ks] = *(const short8*)(Ph + rowb * PST + ks * 32 + kb * 8);
            Bl[ks] = *(const short8*)(Pl + rowb * PST + ks * 32 + kb * 8);
        }
    }

    float cmrun = -INFINITY;              // colmax for col = lane&15 of this wave's l-tile
    for (int a0 = 0; a0 < n; a0 += XT) {
        __syncthreads();   // prior Xh/Xl reads + rm_lds reads complete
        {
            const float4* xsrc = (const float4*)(X + (size_t)s * D);
            for (int i = tid; i < XT * (D / 4); i += 256) {
                const int row = i >> 5, q = (i & 31) * 4;
                const int atom = a0 + row;
                float4 v = {0.f, 0.f, 0.f, 0.f};
                if (atom < n) v = xsrc[(size_t)atom * (D / 4) + (i & 31)];
                ushort4 h, lo;
                h.x = f2bf(v.x); lo.x = f2bf(v.x - bf2f(h.x));
                h.y = f2bf(v.y); lo.y = f2bf(v.y - bf2f(h.y));
                h.z = f2bf(v.z); lo.z = f2bf(v.z - bf2f(h.z));
                h.w = f2bf(v.w); lo.w = f2bf(v.w - bf2f(h.w));
                *(ushort4*)(Xh + row * PST + q) = h;
                *(ushort4*)(Xl + row * PST + q) = lo;
            }
        }
        __syncthreads();

        #pragma unroll
        for (int mt = 0; mt < 2; ++mt) {
            f32x4 acc = {0.f, 0.f, 0.f, 0.f};
            const int rowa = mt * 16 + col;
            #pragma unroll
            for (int ks = 0; ks < 4; ++ks) {
                short8 Ah = *(const short8*)(Xh + rowa * PST + ks * 32 + kb * 8);
                short8 Al = *(const short8*)(Xl + rowa * PST + ks * 32 + kb * 8);
                acc = __builtin_amdgcn_mfma_f32_16x16x32_bf16(Ah, Bh[ks], acc, 0, 0, 0);
                acc = __builtin_amdgcn_mfma_f32_16x16x32_bf16(Ah, Bl[ks], acc, 0, 0, 0);
                acc = __builtin_amdgcn_mfma_f32_16x16x32_bf16(Al, Bh[ks], acc, 0, 0, 0);
            }
            // rowmax over this wave's 16 cols (lanes sharing a row differ in bits 0..3)
            float r0 = acc[0], r1 = acc[1], r2 = acc[2], r3 = acc[3];
            #pragma unroll
            for (int off = 1; off <= 8; off <<= 1) {
                r0 = fmaxf(r0, __shfl_xor(r0, off));
                r1 = fmaxf(r1, __shfl_xor(r1, off));
                r2 = fmaxf(r2, __shfl_xor(r2, off));
                r3 = fmaxf(r3, __shfl_xor(r3, off));
            }
            if (col == 0) {
                float4 rv; rv.x = r0; rv.y = r1; rv.z = r2; rv.w = r3;
                *(float4*)(rm_lds + w * 32 + mt * 16 + kb * 4) = rv;
            }
            // colmax over rows (mask padded atoms)
            const int rbase = a0 + mt * 16 + kb * 4;
            float cm = -INFINITY;
            if (rbase + 0 < n) cm = fmaxf(cm, acc[0]);
            if (rbase + 1 < n) cm = fmaxf(cm, acc[1]);
            if (rbase + 2 < n) cm = fmaxf(cm, acc[2]);
            if (rbase + 3 < n) cm = fmaxf(cm, acc[3]);
            cm = fmaxf(cm, __shfl_xor(cm, 16));
            cm = fmaxf(cm, __shfl_xor(cm, 32));
            cmrun = fmaxf(cmrun, cm);
        }
        __syncthreads();   // rm_lds writes from all 4 waves visible
        if (tid < XT) {
            const int atom = a0 + tid;
            if (atom < n) {
                float m = fmaxf(fmaxf(rm_lds[tid], rm_lds[32 + tid]),
                                fmaxf(rm_lds[64 + tid], rm_lds[96 + tid]));
                rowmaxp[(size_t)(s + atom) * NCHUNK + chunk] = m;
            }
        }
    }

    // epilogue: ews[l] = exp(colmax) ; prot-pool partial from LDS hi+lo
    float* ews  = (float*)(lds + 34816);   // overlay on Xh (dead now)
    float* psum = ews + 64;                // [2][128]
    __syncthreads();
    if (lane < 16) ews[w * 16 + lane] = expf(cmrun);
    __syncthreads();
    {
        const int dd = tid & 127, hh = tid >> 7;
        float sacc = 0.f;
        #pragma unroll 8
        for (int l = hh * 32; l < hh * 32 + 32; ++l)
            sacc += ews[l] * (bf2f(Ph[l * PST + dd]) + bf2f(Pl[l * PST + dd]));
        psum[hh * 128 + dd] = sacc;
    }
    __syncthreads();
    if (tid < 128)
        ppart[(size_t)(b * NCHUNK + chunk) * D + tid] = psum[tid] + psum[128 + tid];
    if (tid < 64) {
        float v = ews[tid];
        #pragma unroll
        for (int off = 32; off >= 1; off >>= 1) v += __shfl_xor(v, off);
        if (tid == 0) eWpart[b * NCHUNK + chunk] = v;
    }
}

// ---------- K3: slim per-molecule pools -> HcT [256][64] ----------
__global__ __launch_bounds__(256) void k3_pool(const float* __restrict__ atom_embed,
                                               const int* __restrict__ splits,
                                               const float* __restrict__ rowmaxp,
                                               const float* __restrict__ ppart,
                                               const float* __restrict__ eWpart,
                                               float* __restrict__ HcT) {
    __shared__ float red[4];
    __shared__ float coef[512];
    __shared__ float4 pred[8][32];
    const int tid = threadIdx.x;
    const int b = blockIdx.x;
    const int s = lb_dev(splits, A_N, b);
    const int e = lb_dev(splits, A_N, b + 1);
    const int n = e - s;

    float local = 0.f;
    for (int j = tid; j < n; j += 256) {
        const float* rp = rowmaxp + (size_t)(s + j) * NCHUNK;
        float m = rp[0];
        #pragma unroll
        for (int c = 1; c < NCHUNK; ++c) m = fmaxf(m, rp[c]);
        local += expf(m);
    }
    const float Sc = blk_sum(local, red, tid);

    const int d4 = tid & 31;   // float4 column
    const int ag = tid >> 5;   // 0..7 atom group
    const float4* ae4 = reinterpret_cast<const float4*>(atom_embed);
    float4 pool = {0.f, 0.f, 0.f, 0.f};
    for (int t0 = 0; t0 < n; t0 += 512) {
        const int cnt = min(512, n - t0);
        __syncthreads();
        for (int j = tid; j < cnt; j += 256) {
            const float* rp = rowmaxp + (size_t)(s + t0 + j) * NCHUNK;
            float m = rp[0];
            #pragma unroll
            for (int c = 1; c < NCHUNK; ++c) m = fmaxf(m, rp[c]);
            coef[j] = expf(m) / Sc;
        }
        __syncthreads();
        for (int j = ag; j < cnt; j += 8) {
            const float c = coef[j];
            const float4 v = ae4[(size_t)(s + t0 + j) * (D / 4) + d4];
            pool.x += c * v.x; pool.y += c * v.y; pool.z += c * v.z; pool.w += c * v.w;
        }
    }
    __syncthreads();
    pred[ag][d4] = pool;
    __syncthreads();
    if (ag == 0) {
        float4 acc = pred[0][d4];
        #pragma unroll
        for (int gg = 1; gg < 8; ++gg) {
            const float4 t = pred[gg][d4];
            acc.x += t.x; acc.y += t.y; acc.z += t.z; acc.w += t.w;
        }
        HcT[(size_t)(d4 * 4 + 0) * B_N + b] = acc.x;
        HcT[(size_t)(d4 * 4 + 1) * B_N + b] = acc.y;
        HcT[(size_t)(d4 * 4 + 2) * B_N + b] = acc.z;
        HcT[(size_t)(d4 * 4 + 3) * B_N + b] = acc.w;
    }
    if (tid < 128) {
        float v = 0.f, ez = 0.f;
        #pragma unroll
        for (int c = 0; c < NCHUNK; ++c) {
            v  += ppart[(size_t)(b * NCHUNK + c) * D + tid];
            ez += eWpart[b * NCHUNK + c];
        }
        HcT[(size_t)(D + tid) * B_N + b] = v / ez;
    }
}

// ---------- K4: H1T = relu(Hc @ W1 + b1)^T ----------
__global__ __launch_bounds__(256) void k4_h1(const float* __restrict__ HcT,
                                             const float* __restrict__ W1,
                                             const float* __restrict__ b1,
                                             float* __restrict__ H1T) {
    __shared__ float hr[4][64];
    const int tid = threadIdx.x;
    const int m = tid & 63;
    const int jh = (tid >> 6) & 1;
    const int kh = tid >> 7;
    const int j = blockIdx.x * 2 + jh;
    float acc = 0.f;
    const int k0 = kh * 128;
    #pragma unroll 8
    for (int k = k0; k < k0 + 128; ++k)
        acc += HcT[(size_t)k * B_N + m] * W1[(size_t)k * H1_N + j];
    hr[jh * 2 + kh][m] = acc;
    __syncthreads();
    if (kh == 0)
        H1T[(size_t)j * B_N + m] = fmaxf(hr[jh * 2][m] + hr[jh * 2 + 1][m] + b1[j], 0.f);
}

// ---------- K5: H2 + output atomics ----------
__global__ __launch_bounds__(256) void k5_h2(const float* __restrict__ H1T,
                                             const float* __restrict__ W2,
                                             const float* __restrict__ b2,
                                             const float* __restrict__ Wo,
                                             float* __restrict__ out) {
    __shared__ float hr[4][64];
    const int tid = threadIdx.x;
    const int m = tid & 63;
    const int kq = tid >> 6;
    const int j = blockIdx.x;
    float acc = 0.f;
    const int k0 = kq * 128;
    #pragma unroll 8
    for (int k = k0; k < k0 + 128; ++k)
        acc += H1T[(size_t)k * B_N + m] * W2[(size_t)k * H2_N + j];
    hr[kq][m] = acc;
    __syncthreads();
    if (kq == 0) {
        const float h2 = fmaxf(hr[0][m] + hr[1][m] + hr[2][m] + hr[3][m] + b2[j], 0.f);
        atomicAdd(out + m, h2 * Wo[j]);
    }
}

extern "C" void kernel_launch(void* const* d_in, const int* in_sizes, int n_in,
                              void* d_out, int out_size, void* d_ws, size_t ws_size,
                              hipStream_t stream) {
    const float* atom_embed = (const float*)d_in[0];
    const float* prot       = (const float*)d_in[1];
    const int*   splits     = (const int*)d_in[2];
    const float* W_att      = (const float*)d_in[3];
    const float* W1         = (const float*)d_in[4];
    const float* b1         = (const float*)d_in[5];
    const float* W2         = (const float*)d_in[6];
    const float* b2         = (const float*)d_in[7];
    const float* Wo         = (const float*)d_in[8];
    const float* bo         = (const float*)d_in[9];
    float* out = (float*)d_out;

    float* ws = (float*)d_ws;
    float* X       = ws;  ws += A_N * D;             // 262144
    float* rowmaxp = ws;  ws += A_N * NCHUNK;        // 16384
    float* ppart   = ws;  ws += B_N * NCHUNK * D;    // 65536
    float* eWpart  = ws;  ws += B_N * NCHUNK;        // 512
    float* HcT     = ws;  ws += 2 * D * B_N;         // 16384
    float* H1T     = ws;  ws += H1_N * B_N;          // 32768

    hipLaunchKernelGGL(k1_xmul,  dim3(A_N / 8),      dim3(256), 0, stream,
                       atom_embed, W_att, bo, X, out);
    hipLaunchKernelGGL(k2_scores,dim3(B_N * NCHUNK), dim3(256), 0, stream,
                       X, prot, splits, rowmaxp, ppart, eWpart);
    hipLaunchKernelGGL(k3_pool,  dim3(B_N),          dim3(256), 0, stream,
                       atom_embed, splits, rowmaxp, ppart, eWpart, HcT);
    hipLaunchKernelGGL(k4_h1,    dim3(H1_N / 2),     dim3(256), 0, stream, HcT, W1, b1, H1T);
    hipLaunchKernelGGL(k5_h2,    dim3(H2_N),         dim3(256), 0, stream, H1T, W2, b2, Wo, out);
}